// Round 5
// baseline (798.856 us; speedup 1.0000x reference)
//
#include <hip/hip_runtime.h>
#include <cstdint>

#define DEV static __device__ __forceinline__

typedef float f4v __attribute__((ext_vector_type(4)));
typedef short s8v __attribute__((ext_vector_type(8)));

// ---------- helpers ----------
DEV ushort f2bf(float f) {
  uint32_t u = __float_as_uint(f);
  uint32_t r = (u + 0x7FFFu + ((u >> 16) & 1u)) >> 16;   // RTNE
  return (ushort)r;
}
DEV float bf2f(ushort h) { return __uint_as_float(((uint32_t)h) << 16); }

DEV void lds_cp16(const void* g, void* l) {
  __builtin_amdgcn_global_load_lds((const __attribute__((address_space(1))) void*)g,
                                   (__attribute__((address_space(3))) void*)l, 16, 0, 0);
}

// ---------- constants ----------
#define BB 8
#define NN 1025
#define CC 1024
#define HH 16
#define DD 64
#define MM 25
#define KK 25
#define MROWS 8200          // B*N
#define SCALE 0.125f

// ---------- split x into bf16 hi/lo ----------
__global__ void split_x_kernel(const float* __restrict__ x, ushort* __restrict__ hi,
                               ushort* __restrict__ lo, int n4) {
  int i = blockIdx.x * 256 + threadIdx.x;
  if (i >= n4) return;
  float4 f = ((const float4*)x)[i];
  ushort4 h, l;
  h.x = f2bf(f.x); l.x = f2bf(f.x - bf2f(h.x));
  h.y = f2bf(f.y); l.y = f2bf(f.y - bf2f(h.y));
  h.z = f2bf(f.z); l.z = f2bf(f.z - bf2f(h.z));
  h.w = f2bf(f.w); l.w = f2bf(f.w - bf2f(h.w));
  ((ushort4*)hi)[i] = h;
  ((ushort4*)lo)[i] = l;
}

// ---------- transpose W[K][N] -> Wt[N][K] bf16 hi (+optional lo) ----------
__global__ void transpose_split_kernel(const float* __restrict__ W, ushort* __restrict__ hi,
                                       ushort* __restrict__ lo, int K, int N) {
  __shared__ float tile[32][33];
  int nb = blockIdx.x * 32, kb = blockIdx.y * 32;
  int tx = threadIdx.x, ty = threadIdx.y;      // 32x8
  for (int r = ty; r < 32; r += 8) tile[r][tx] = W[(size_t)(kb + r) * N + nb + tx];
  __syncthreads();
  for (int r = ty; r < 32; r += 8) {
    float f = tile[tx][r];                     // W[kb+tx][nb+r] -> Wt[nb+r][kb+tx]
    ushort h = f2bf(f);
    hi[(size_t)(nb + r) * K + kb + tx] = h;
    if (lo) lo[(size_t)(nb + r) * K + kb + tx] = f2bf(f - bf2f(h));
  }
}

// ---------- main MFMA GEMM: C[M][N] = A[M][K] * Bt[N][K]^T  (bf16x3 for n < loN) ----------
// LDS layout: row-major 128 rows x 4 slots of 16B; slot s of row r holds global
// k-group s ^ ((r>>1)&3)  (XOR swizzle -> b128 fragment reads are 2-way max, free)
__global__ __launch_bounds__(256)
void gemm_split_kernel(const ushort* __restrict__ Ah, const ushort* __restrict__ Al,
                       const ushort* __restrict__ Bh, const ushort* __restrict__ Bl,
                       float* __restrict__ C, const float* __restrict__ bias,
                       int M, int N, int K, int loN) {
  __shared__ ushort sm[4 * 4096];              // Ah | Al | Bh | Bl tiles, 128x32 each
  ushort* sAh = sm;
  ushort* sAl = sm + 4096;
  ushort* sBh = sm + 8192;
  ushort* sBl = sm + 12288;
  const int t = threadIdx.x;
  const int m0 = blockIdx.y * 128, n0 = blockIdx.x * 128;
  const bool three = (n0 < loN);
  const int lane = t & 63, wid = t >> 6;
  const int wy = wid >> 1, wx = wid & 1;       // 2x2 waves of 64x64
  const int lrow = lane & 15, lq = lane >> 4;
  const int slot = lq ^ ((lrow >> 1) & 3);     // fragment read swizzle

  f4v acc[4][4];
#pragma unroll
  for (int a = 0; a < 4; ++a)
#pragma unroll
    for (int b = 0; b < 4; ++b) acc[a][b] = (f4v)0.f;

  for (int k0 = 0; k0 < K; k0 += 32) {
#pragma unroll
    for (int i = 0; i < 2; ++i) {
      int e = i * 256 + t;
      int row = e >> 2;
      int cgs = (e & 3) ^ ((e >> 3) & 3);      // staged k-group (XOR swizzle)
      int ebase = i * 256 + (t & 192);         // wave-uniform base
      size_t aoff = (size_t)min(m0 + row, M - 1) * K + k0 + cgs * 8;
      size_t boff = (size_t)(n0 + row) * K + k0 + cgs * 8;
      lds_cp16(Ah + aoff, sAh + (size_t)ebase * 8);
      lds_cp16(Bh + boff, sBh + (size_t)ebase * 8);
      if (three) {
        lds_cp16(Al + aoff, sAl + (size_t)ebase * 8);
        lds_cp16(Bl + boff, sBl + (size_t)ebase * 8);
      }
    }
    __syncthreads();
    s8v fa[4], fb[4];
#pragma unroll
    for (int u = 0; u < 4; ++u) {
      fa[u] = *(const s8v*)(sAh + (((wy * 64 + u * 16 + lrow) * 4 + slot) * 8));
      fb[u] = *(const s8v*)(sBh + (((wx * 64 + u * 16 + lrow) * 4 + slot) * 8));
    }
#pragma unroll
    for (int mt = 0; mt < 4; ++mt)
#pragma unroll
      for (int nt = 0; nt < 4; ++nt)
        acc[mt][nt] = __builtin_amdgcn_mfma_f32_16x16x32_bf16(fa[mt], fb[nt], acc[mt][nt], 0, 0, 0);
    if (three) {
      s8v la[4], lb[4];
#pragma unroll
      for (int u = 0; u < 4; ++u) {
        la[u] = *(const s8v*)(sAl + (((wy * 64 + u * 16 + lrow) * 4 + slot) * 8));
        lb[u] = *(const s8v*)(sBl + (((wx * 64 + u * 16 + lrow) * 4 + slot) * 8));
      }
#pragma unroll
      for (int mt = 0; mt < 4; ++mt)
#pragma unroll
        for (int nt = 0; nt < 4; ++nt) {
          acc[mt][nt] = __builtin_amdgcn_mfma_f32_16x16x32_bf16(fa[mt], lb[nt], acc[mt][nt], 0, 0, 0);
          acc[mt][nt] = __builtin_amdgcn_mfma_f32_16x16x32_bf16(la[mt], fb[nt], acc[mt][nt], 0, 0, 0);
        }
    }
    __syncthreads();
  }
  // epilogue: C/D layout col=lane&15, row=(lane>>4)*4+i  [m89/m91-verified]
#pragma unroll
  for (int mt = 0; mt < 4; ++mt) {
#pragma unroll
    for (int i = 0; i < 4; ++i) {
      int r = m0 + wy * 64 + mt * 16 + lq * 4 + i;
      if (r < M) {
#pragma unroll
        for (int nt = 0; nt < 4; ++nt) {
          int c = n0 + wx * 64 + nt * 16 + lrow;
          float v = acc[mt][nt][i];
          if (bias) v += bias[c];
          C[(size_t)r * N + c] = v;
        }
      }
    }
  }
}

// ---------- adaptive-pool router tokens from q (1024 threads: 1 channel/thread) ----------
__global__ __launch_bounds__(1024)
void pool_router_kernel(const float* __restrict__ qkv, float* __restrict__ router) {
  int bm = blockIdx.x;                 // b*25 + m
  int b = bm / 25, m = bm % 25;
  int p = m / 5, q = m % 5;
  int sp = (p * 32) / 5, ep = ((p + 1) * 32 + 4) / 5;
  int sq = (q * 32) / 5, eq = ((q + 1) * 32 + 4) / 5;
  float inv = 1.0f / (float)((ep - sp) * (eq - sq));
  int c = threadIdx.x;
  float s0 = 0.f;
  for (int hh = sp; hh < ep; ++hh)
    for (int ww = sq; ww < eq; ++ww)
      s0 += qkv[(size_t)(b * NN + hh * 32 + ww) * 3072 + c];
  router[(size_t)bm * 1024 + c] = s0 * inv;
}

// ---------- router logits: rlog = r.k, gate = r.q  (fp32); 16 n-slices ----------
__global__ __launch_bounds__(256)
void router_logits_kernel(const float* __restrict__ qkv, const float* __restrict__ router,
                          float* __restrict__ rlog, float* __restrict__ gate) {
  int bh = blockIdx.x;                 // b*16+h
  int b = bh >> 4, h = bh & 15;
  int s = blockIdx.y;                  // 16 slices of 64 (last: 65)
  int t = threadIdx.x;
  if (t >= 250) return;
  int m = t % 25, cc = t / 25;         // cc 0..9
  float r[64];
  const float* rp = router + (size_t)(b * 25 + m) * 1024 + h * 64;
#pragma unroll
  for (int dg = 0; dg < 16; ++dg) {
    float4 v = *(const float4*)(rp + dg * 4);
    r[dg * 4 + 0] = v.x; r[dg * 4 + 1] = v.y; r[dg * 4 + 2] = v.z; r[dg * 4 + 3] = v.w;
  }
  int base = s * 64;
  int seglen = (s == 15) ? 65 : 64;
  int nbase = base + cc * 7;
  int nend = min(base + seglen, nbase + 7);
  size_t orow = (size_t)(bh * 25 + m) * NN;
  for (int n = nbase; n < nend; ++n) {
    const float* qr = qkv + (size_t)(b * NN + n) * 3072 + h * 64;
    float aq = 0.f, ak = 0.f;
#pragma unroll
    for (int dg = 0; dg < 16; ++dg) {
      float4 qv = *(const float4*)(qr + dg * 4);
      float4 kv = *(const float4*)(qr + 1024 + dg * 4);
      aq += r[dg * 4 + 0] * qv.x + r[dg * 4 + 1] * qv.y + r[dg * 4 + 2] * qv.z + r[dg * 4 + 3] * qv.w;
      ak += r[dg * 4 + 0] * kv.x + r[dg * 4 + 1] * kv.y + r[dg * 4 + 2] * kv.z + r[dg * 4 + 3] * kv.w;
    }
    gate[orow + n] = aq;
    rlog[orow + n] = ak;
  }
}

// ---------- top-25 of each rlog row + softmax row stats (one wave per row) ----------
__global__ void topk2_kernel(const float* __restrict__ rlog, int* __restrict__ topk,
                             float* __restrict__ rowMax, float* __restrict__ rowRcp) {
  int row = blockIdx.x;                // (b*16+h)*25+m
  int l = threadIdx.x;                 // 0..63
  const float* src = rlog + (size_t)row * NN;
  float vals[17];
#pragma unroll
  for (int i = 0; i < 17; ++i) {
    int n = l + i * 64;
    vals[i] = (n < NN) ? src[n] : -INFINITY;
  }
  {
    float mx = vals[0];
#pragma unroll
    for (int i = 1; i < 17; ++i) mx = fmaxf(mx, vals[i]);
#pragma unroll
    for (int off = 32; off; off >>= 1) mx = fmaxf(mx, __shfl_xor(mx, off));
    float mxs = mx * SCALE;
    float sum = 0.f;
#pragma unroll
    for (int i = 0; i < 17; ++i) sum += __expf(vals[i] * SCALE - mxs);  // exp(-inf)=0
#pragma unroll
    for (int off = 32; off; off >>= 1) sum += __shfl_xor(sum, off);
    if (l == 0) { rowMax[row] = mxs; rowRcp[row] = 1.0f / sum; }
  }
  int* out = topk + row * 25;
  for (int r = 0; r < 25; ++r) {
    float best = vals[0]; int bi = 0;
#pragma unroll
    for (int i = 1; i < 17; ++i)
      if (vals[i] > best) { best = vals[i]; bi = i; }
    int bn = l + bi * 64;
#pragma unroll
    for (int off = 32; off; off >>= 1) {
      float ov = __shfl_down(best, off);
      int on = __shfl_down(bn, off);
      if (ov > best || (ov == best && on < bn)) { best = ov; bn = on; }
    }
    bn = __shfl(bn, 0);
    if (l == 0) out[r] = bn;
    if ((bn & 63) == l) vals[bn >> 6] = -INFINITY;
  }
}

// ---------- agent value v3: wave per (bh, m); lane = d; zero LDS, coalesced v ----------
__global__ __launch_bounds__(256)
void agent_value3_kernel(const float* __restrict__ qkv, const float* __restrict__ rlog,
                         const float* __restrict__ rowMax, const float* __restrict__ rowRcp,
                         float* __restrict__ av) {
  int bh = blockIdx.x, g = blockIdx.y;
  int w = threadIdx.x >> 6, l = threadIdx.x & 63;
  int m = g * 4 + w;
  if (m >= 25) return;
  int b = bh >> 4, h = bh & 15;
  const float* src = rlog + (size_t)(bh * 25 + m) * NN;   // wave-uniform -> s_load
  float mxs = rowMax[bh * 25 + m], rcp = rowRcp[bh * 25 + m];
  const float* vbase = qkv + (size_t)b * NN * 3072 + 2048 + h * 64 + l;
  float acc = 0.f;
#pragma unroll 4
  for (int n = 0; n < NN; ++n) {
    float p = __expf(src[n] * SCALE - mxs);
    acc += p * vbase[(size_t)n * 3072];
  }
  av[(size_t)(bh * 25 + m) * 64 + l] = acc * rcp;
}

// ---------- expert assignment + gate transpose + per-expert query lists ----------
__global__ __launch_bounds__(256)
void assign_kernel(const float* __restrict__ gate, float* __restrict__ gateT,
                   int* __restrict__ cnt, int* __restrict__ qlist) {
  int bh = blockIdx.x, sl = blockIdx.y;
  int n = sl * 205 + threadIdx.x;
  if (threadIdx.x >= 205) return;              // 5 x 205 = 1025
  float best = -INFINITY; int bi = 0;
#pragma unroll
  for (int m = 0; m < 25; ++m) {
    float v = gate[(size_t)(bh * 25 + m) * NN + n];
    gateT[((size_t)bh * NN + n) * 25 + m] = v;
    if (v > best) { best = v; bi = m; }        // strict > : first-max, matches jnp.argmax
  }
  int pos = atomicAdd(&cnt[bh * 25 + bi], 1);
  qlist[(bh * 25 + bi) * NN + pos] = n;
}

// ---------- mixed attention v5: lane-per-query, ONE chunk per block (z-split) ----------
__global__ __launch_bounds__(64)
void mixed_attn5_kernel(const float* __restrict__ qkv, const float* __restrict__ gateT,
                        const int* __restrict__ topk, const float* __restrict__ av,
                        const int* __restrict__ cnt, const int* __restrict__ qlist,
                        ushort* __restrict__ attn) {
  int e = blockIdx.x, bh = blockIdx.y;
  int c0 = blockIdx.z * 64;
  int ce = cnt[bh * 25 + e];
  if (c0 >= ce) return;                // empty chunk -> cheap exit (imbalance fix)
  int b = bh >> 4, h = bh & 15;
  int l = threadIdx.x;                 // 64 threads = 1 wave
  const int* tkp = topk + bh * 625 + e * 25;
  const int* ql = qlist + (bh * 25 + e) * NN;
  const float* qb = qkv + (size_t)b * NN * 3072 + h * 64;
  const float* avb = av + (size_t)bh * 25 * 64;

  int qi = c0 + l;
  bool act = qi < ce;
  int n = ql[act ? qi : c0];
  const float* qr = qb + (size_t)n * 3072;
  float4 q4[16];
#pragma unroll
  for (int d4 = 0; d4 < 16; ++d4) q4[d4] = *(const float4*)(qr + d4 * 4);
  float w[50];
  float mx = -INFINITY, tot = 0.f;
  const float* gr = gateT + ((size_t)bh * NN + n) * 25;
#pragma unroll
  for (int m = 0; m < 25; ++m) {
    float v = gr[m] * SCALE;
    w[m] = v;
    float nm = fmaxf(mx, v);
    tot = tot * __expf(mx - nm) + __expf(v - nm);
    mx = nm;
  }
#pragma unroll
  for (int j = 0; j < 25; ++j) {
    const float* kr = qb + (size_t)tkp[j] * 3072 + 1024;   // wave-uniform
    float a = 0.f;
#pragma unroll
    for (int d4 = 0; d4 < 16; ++d4) {
      float4 k4 = *(const float4*)(kr + d4 * 4);
      a += q4[d4].x * k4.x + q4[d4].y * k4.y + q4[d4].z * k4.z + q4[d4].w * k4.w;
    }
    float v = a * SCALE;
    w[25 + j] = v;
    float nm = fmaxf(mx, v);
    tot = tot * __expf(mx - nm) + __expf(v - nm);
    mx = nm;
  }
  float rcp = 1.0f / tot;
#pragma unroll
  for (int i = 0; i < 50; ++i) w[i] = __expf(w[i] - mx) * rcp;
  // output in two d-halves (caps live VGPRs)
#pragma unroll
  for (int half = 0; half < 2; ++half) {
    float4 o[8];
#pragma unroll
    for (int d4 = 0; d4 < 8; ++d4) o[d4] = make_float4(0.f, 0.f, 0.f, 0.f);
#pragma unroll
    for (int m = 0; m < 25; ++m) {
      const float* src = avb + m * 64 + half * 32;         // wave-uniform
      float wv = w[m];
#pragma unroll
      for (int d4 = 0; d4 < 8; ++d4) {
        float4 a4 = *(const float4*)(src + d4 * 4);
        o[d4].x += wv * a4.x; o[d4].y += wv * a4.y;
        o[d4].z += wv * a4.z; o[d4].w += wv * a4.w;
      }
    }
#pragma unroll
    for (int j = 0; j < 25; ++j) {
      const float* src = qb + (size_t)tkp[j] * 3072 + 2048 + half * 32;  // wave-uniform
      float wv = w[25 + j];
#pragma unroll
      for (int d4 = 0; d4 < 8; ++d4) {
        float4 a4 = *(const float4*)(src + d4 * 4);
        o[d4].x += wv * a4.x; o[d4].y += wv * a4.y;
        o[d4].z += wv * a4.z; o[d4].w += wv * a4.w;
      }
    }
    if (act) {
      ushort* orow = attn + (size_t)(b * NN + n) * 1024 + h * 64 + half * 32;
#pragma unroll
      for (int d4 = 0; d4 < 8; ++d4) {
        ushort4 u;
        u.x = f2bf(o[d4].x); u.y = f2bf(o[d4].y);
        u.z = f2bf(o[d4].z); u.w = f2bf(o[d4].w);
        *(ushort4*)(orow + d4 * 4) = u;
      }
    }
  }
}

// ---------- launch ----------
extern "C" void kernel_launch(void* const* d_in, const int* in_sizes, int n_in,
                              void* d_out, int out_size, void* d_ws, size_t ws_size,
                              hipStream_t stream) {
  const float* x = (const float*)d_in[0];
  const float* Wqkv = (const float*)d_in[1];
  const float* Wproj = (const float*)d_in[2];
  const float* bproj = (const float*)d_in[3];

  char* ws = (char*)d_ws;
  size_t off = 0;
  float* qkv = (float*)(ws + off);      off += (size_t)MROWS * 3072 * 4;    // 100,761,600
  ushort* xh = (ushort*)(ws + off);     off += (size_t)MROWS * 1024 * 2;    // 16,793,600
  ushort* xl = (ushort*)(ws + off);     off += (size_t)MROWS * 1024 * 2;
  ushort* Wth = (ushort*)(ws + off);    off += (size_t)3072 * 1024 * 2;     // 6,291,456
  ushort* Wtl = (ushort*)(ws + off);    off += (size_t)3072 * 1024 * 2;
  ushort* WpT = (ushort*)(ws + off);    off += (size_t)1024 * 1024 * 2;     // 2,097,152
  float* router = (float*)(ws + off);   off += (size_t)BB * 25 * 1024 * 4;  // 819,200
  float* rlog = (float*)(ws + off);     off += (size_t)BB * HH * 25 * NN * 4; // 13,120,000
  float* gate = (float*)(ws + off);     off += (size_t)BB * HH * 25 * NN * 4;
  int* topk = (int*)(ws + off);         off += (size_t)BB * HH * 25 * 25 * 4; // 320,000
  float* av = (float*)(ws + off);       off += (size_t)BB * HH * 25 * 64 * 4; // 819,200
  ushort* attn = (ushort*)(ws + off);   off += (size_t)MROWS * 1024 * 2;
  float* rowMax = (float*)(ws + off);   off += (size_t)BB * HH * 25 * 4;    // 12,800
  float* rowRcp = (float*)(ws + off);   off += (size_t)BB * HH * 25 * 4;

  // xh/xl are dead after the qkv GEMM -> reuse for routing metadata
  float* gateT = (float*)xh;                               // 13,120,000 B (<= 16,793,600)
  int* cnt = (int*)((char*)xh + 13120000);                 // 12,800 B
  int* qlist = (int*)xl;                                   // 13,120,000 B

  split_x_kernel<<<8200, 256, 0, stream>>>(x, xh, xl, 2099200);
  transpose_split_kernel<<<dim3(96, 32), dim3(32, 8), 0, stream>>>(Wqkv, Wth, Wtl, 1024, 3072);
  transpose_split_kernel<<<dim3(32, 32), dim3(32, 8), 0, stream>>>(Wproj, WpT, nullptr, 1024, 1024);
  // qkv = x @ Wqkv : bf16x3 for q,k columns (<2048), plain bf16 for v columns
  gemm_split_kernel<<<dim3(24, 65), 256, 0, stream>>>(xh, xl, Wth, Wtl, qkv, nullptr,
                                                      MROWS, 3072, 1024, 2048);
  pool_router_kernel<<<BB * 25, 1024, 0, stream>>>(qkv, router);
  router_logits_kernel<<<dim3(128, 16), 256, 0, stream>>>(qkv, router, rlog, gate);
  hipMemsetAsync(cnt, 0, 3200 * 4, stream);
  assign_kernel<<<dim3(128, 5), 256, 0, stream>>>(gate, gateT, cnt, qlist);
  topk2_kernel<<<BB * HH * 25, 64, 0, stream>>>(rlog, topk, rowMax, rowRcp);
  agent_value3_kernel<<<dim3(128, 7), 256, 0, stream>>>(qkv, rlog, rowMax, rowRcp, av);
  mixed_attn5_kernel<<<dim3(25, 128, 17), 64, 0, stream>>>(qkv, gateT, topk, av, cnt, qlist, attn);
  // out = attn @ Wproj + bproj : plain bf16
  gemm_split_kernel<<<dim3(8, 65), 256, 0, stream>>>(attn, attn, WpT, WpT, (float*)d_out, bproj,
                                                     MROWS, 1024, 1024, 0);
}

// Round 6
// 605.261 us; speedup vs baseline: 1.3199x; 1.3199x over previous
//
#include <hip/hip_runtime.h>
#include <cstdint>

#define DEV static __device__ __forceinline__

typedef float f4v __attribute__((ext_vector_type(4)));
typedef short s8v __attribute__((ext_vector_type(8)));

// ---------- helpers ----------
DEV ushort f2bf(float f) {
  uint32_t u = __float_as_uint(f);
  uint32_t r = (u + 0x7FFFu + ((u >> 16) & 1u)) >> 16;   // RTNE
  return (ushort)r;
}
DEV float bf2f(ushort h) { return __uint_as_float(((uint32_t)h) << 16); }

DEV void lds_cp16(const void* g, void* l) {
  __builtin_amdgcn_global_load_lds((const __attribute__((address_space(1))) void*)g,
                                   (__attribute__((address_space(3))) void*)l, 16, 0, 0);
}

// ---------- constants ----------
#define BB 8
#define NN 1025
#define CC 1024
#define HH 16
#define DD 64
#define MM 25
#define KK 25
#define MROWS 8200          // B*N
#define SCALE 0.125f

// ---------- split x into bf16 hi/lo ----------
__global__ void split_x_kernel(const float* __restrict__ x, ushort* __restrict__ hi,
                               ushort* __restrict__ lo, int n4) {
  int i = blockIdx.x * 256 + threadIdx.x;
  if (i >= n4) return;
  float4 f = ((const float4*)x)[i];
  ushort4 h, l;
  h.x = f2bf(f.x); l.x = f2bf(f.x - bf2f(h.x));
  h.y = f2bf(f.y); l.y = f2bf(f.y - bf2f(h.y));
  h.z = f2bf(f.z); l.z = f2bf(f.z - bf2f(h.z));
  h.w = f2bf(f.w); l.w = f2bf(f.w - bf2f(h.w));
  ((ushort4*)hi)[i] = h;
  ((ushort4*)lo)[i] = l;
}

// ---------- transpose W[K][N] -> Wt[N][K] bf16 hi (+optional lo) ----------
__global__ void transpose_split_kernel(const float* __restrict__ W, ushort* __restrict__ hi,
                                       ushort* __restrict__ lo, int K, int N) {
  __shared__ float tile[32][33];
  int nb = blockIdx.x * 32, kb = blockIdx.y * 32;
  int tx = threadIdx.x, ty = threadIdx.y;      // 32x8
  for (int r = ty; r < 32; r += 8) tile[r][tx] = W[(size_t)(kb + r) * N + nb + tx];
  __syncthreads();
  for (int r = ty; r < 32; r += 8) {
    float f = tile[tx][r];                     // W[kb+tx][nb+r] -> Wt[nb+r][kb+tx]
    ushort h = f2bf(f);
    hi[(size_t)(nb + r) * K + kb + tx] = h;
    if (lo) lo[(size_t)(nb + r) * K + kb + tx] = f2bf(f - bf2f(h));
  }
}

// ---------- main MFMA GEMM: C[M][N] = A[M][K] * Bt[N][K]^T  (bf16x3 for n < loN) ----------
// LDS layout: row-major 128 rows x 4 slots of 16B; slot s of row r holds global
// k-group s ^ ((r>>1)&3)  (XOR swizzle -> b128 fragment reads are 2-way max, free)
__global__ __launch_bounds__(256)
void gemm_split_kernel(const ushort* __restrict__ Ah, const ushort* __restrict__ Al,
                       const ushort* __restrict__ Bh, const ushort* __restrict__ Bl,
                       float* __restrict__ C, const float* __restrict__ bias,
                       int M, int N, int K, int loN) {
  __shared__ ushort sm[4 * 4096];              // Ah | Al | Bh | Bl tiles, 128x32 each
  ushort* sAh = sm;
  ushort* sAl = sm + 4096;
  ushort* sBh = sm + 8192;
  ushort* sBl = sm + 12288;
  const int t = threadIdx.x;
  const int m0 = blockIdx.y * 128, n0 = blockIdx.x * 128;
  const bool three = (n0 < loN);
  const int lane = t & 63, wid = t >> 6;
  const int wy = wid >> 1, wx = wid & 1;       // 2x2 waves of 64x64
  const int lrow = lane & 15, lq = lane >> 4;
  const int slot = lq ^ ((lrow >> 1) & 3);     // fragment read swizzle

  f4v acc[4][4];
#pragma unroll
  for (int a = 0; a < 4; ++a)
#pragma unroll
    for (int b = 0; b < 4; ++b) acc[a][b] = (f4v)0.f;

  for (int k0 = 0; k0 < K; k0 += 32) {
#pragma unroll
    for (int i = 0; i < 2; ++i) {
      int e = i * 256 + t;
      int row = e >> 2;
      int cgs = (e & 3) ^ ((e >> 3) & 3);      // staged k-group (XOR swizzle)
      int ebase = i * 256 + (t & 192);         // wave-uniform base
      size_t aoff = (size_t)min(m0 + row, M - 1) * K + k0 + cgs * 8;
      size_t boff = (size_t)(n0 + row) * K + k0 + cgs * 8;
      lds_cp16(Ah + aoff, sAh + (size_t)ebase * 8);
      lds_cp16(Bh + boff, sBh + (size_t)ebase * 8);
      if (three) {
        lds_cp16(Al + aoff, sAl + (size_t)ebase * 8);
        lds_cp16(Bl + boff, sBl + (size_t)ebase * 8);
      }
    }
    __syncthreads();
    s8v fa[4], fb[4];
#pragma unroll
    for (int u = 0; u < 4; ++u) {
      fa[u] = *(const s8v*)(sAh + (((wy * 64 + u * 16 + lrow) * 4 + slot) * 8));
      fb[u] = *(const s8v*)(sBh + (((wx * 64 + u * 16 + lrow) * 4 + slot) * 8));
    }
#pragma unroll
    for (int mt = 0; mt < 4; ++mt)
#pragma unroll
      for (int nt = 0; nt < 4; ++nt)
        acc[mt][nt] = __builtin_amdgcn_mfma_f32_16x16x32_bf16(fa[mt], fb[nt], acc[mt][nt], 0, 0, 0);
    if (three) {
      s8v la[4], lb[4];
#pragma unroll
      for (int u = 0; u < 4; ++u) {
        la[u] = *(const s8v*)(sAl + (((wy * 64 + u * 16 + lrow) * 4 + slot) * 8));
        lb[u] = *(const s8v*)(sBl + (((wx * 64 + u * 16 + lrow) * 4 + slot) * 8));
      }
#pragma unroll
      for (int mt = 0; mt < 4; ++mt)
#pragma unroll
        for (int nt = 0; nt < 4; ++nt) {
          acc[mt][nt] = __builtin_amdgcn_mfma_f32_16x16x32_bf16(fa[mt], lb[nt], acc[mt][nt], 0, 0, 0);
          acc[mt][nt] = __builtin_amdgcn_mfma_f32_16x16x32_bf16(la[mt], fb[nt], acc[mt][nt], 0, 0, 0);
        }
    }
    __syncthreads();
  }
  // epilogue: C/D layout col=lane&15, row=(lane>>4)*4+i  [m89/m91-verified]
#pragma unroll
  for (int mt = 0; mt < 4; ++mt) {
#pragma unroll
    for (int i = 0; i < 4; ++i) {
      int r = m0 + wy * 64 + mt * 16 + lq * 4 + i;
      if (r < M) {
#pragma unroll
        for (int nt = 0; nt < 4; ++nt) {
          int c = n0 + wx * 64 + nt * 16 + lrow;
          float v = acc[mt][nt][i];
          if (bias) v += bias[c];
          C[(size_t)r * N + c] = v;
        }
      }
    }
  }
}

// ---------- adaptive-pool router tokens from q (1024 threads: 1 channel/thread) ----------
__global__ __launch_bounds__(1024)
void pool_router_kernel(const float* __restrict__ qkv, float* __restrict__ router) {
  int bm = blockIdx.x;                 // b*25 + m
  int b = bm / 25, m = bm % 25;
  int p = m / 5, q = m % 5;
  int sp = (p * 32) / 5, ep = ((p + 1) * 32 + 4) / 5;
  int sq = (q * 32) / 5, eq = ((q + 1) * 32 + 4) / 5;
  float inv = 1.0f / (float)((ep - sp) * (eq - sq));
  int c = threadIdx.x;
  float s0 = 0.f;
  for (int hh = sp; hh < ep; ++hh)
    for (int ww = sq; ww < eq; ++ww)
      s0 += qkv[(size_t)(b * NN + hh * 32 + ww) * 3072 + c];
  router[(size_t)bm * 1024 + c] = s0 * inv;
}

// ---------- fused router logits + gate transpose + argmax assign ----------
// grid (128 bh, 17 n-slices of 64); block 256 = 4 waves.
// thread t: n_l = t&63 (local row), w = t>>6 (m stride-4 subset).
__global__ __launch_bounds__(256)
void rg_fused_kernel(const float* __restrict__ qkv, const float* __restrict__ router,
                     float* __restrict__ rlog, float* __restrict__ gateT,
                     int* __restrict__ cnt, int* __restrict__ qlist) {
  __shared__ float sQ[64 * 68];        // pitch 68 -> b128 reads conflict-free
  __shared__ float sK[64 * 68];
  __shared__ float sR[25 * 64];
  __shared__ float sG[64 * 27];        // gate tile, odd-ish pitch
  int bh = blockIdx.x, s = blockIdx.y;
  int b = bh >> 4, h = bh & 15;
  int base = s * 64, seglen = min(64, NN - base);
  int t = threadIdx.x;
  for (int e = t; e < 400; e += 256) {           // r: 25 rows x 16 float4
    int m = e >> 4, c4 = e & 15;
    *(float4*)&sR[m * 64 + c4 * 4] =
        *(const float4*)(router + (size_t)(b * 25 + m) * 1024 + h * 64 + c4 * 4);
  }
  for (int e = t; e < seglen * 16; e += 256) {   // q,k tiles coalesced
    int row = e >> 4, c4 = e & 15;
    const float* src = qkv + (size_t)(b * NN + base + row) * 3072 + h * 64 + c4 * 4;
    *(float4*)&sQ[row * 68 + c4 * 4] = *(const float4*)(src);
    *(float4*)&sK[row * 68 + c4 * 4] = *(const float4*)(src + 1024);
  }
  __syncthreads();
  int nl = t & 63, w = t >> 6;
  if (nl < seglen) {
    float4 rowreg[16];
#pragma unroll
    for (int c4 = 0; c4 < 16; ++c4) rowreg[c4] = *(const float4*)&sQ[nl * 68 + c4 * 4];
    for (int m = w; m < 25; m += 4) {
      const float* rp = &sR[m * 64];
      float a = 0.f;
#pragma unroll
      for (int c4 = 0; c4 < 16; ++c4) {
        float4 r4 = *(const float4*)(rp + c4 * 4);        // broadcast within wave
        a += rowreg[c4].x * r4.x + rowreg[c4].y * r4.y +
             rowreg[c4].z * r4.z + rowreg[c4].w * r4.w;
      }
      sG[nl * 27 + m] = a;
    }
#pragma unroll
    for (int c4 = 0; c4 < 16; ++c4) rowreg[c4] = *(const float4*)&sK[nl * 68 + c4 * 4];
    for (int m = w; m < 25; m += 4) {
      const float* rp = &sR[m * 64];
      float a = 0.f;
#pragma unroll
      for (int c4 = 0; c4 < 16; ++c4) {
        float4 r4 = *(const float4*)(rp + c4 * 4);
        a += rowreg[c4].x * r4.x + rowreg[c4].y * r4.y +
             rowreg[c4].z * r4.z + rowreg[c4].w * r4.w;
      }
      rlog[(size_t)(bh * 25 + m) * NN + base + nl] = a;   // coalesced per m
    }
  }
  __syncthreads();
  if (t < seglen) {
    const float* gp = &sG[t * 27];
    float* gout = gateT + ((size_t)bh * NN + base + t) * 25;
    float best = -INFINITY; int bi = 0;
#pragma unroll
    for (int m = 0; m < 25; ++m) {
      float v = gp[m];
      gout[m] = v;
      if (v > best) { best = v; bi = m; }      // strict > : first-max, matches jnp.argmax
    }
    int pos = atomicAdd(&cnt[bh * 25 + bi], 1);
    qlist[(bh * 25 + bi) * NN + pos] = base + t;
  }
}

// ---------- top-25 of each rlog row + softmax row stats (one wave per row) ----------
__global__ void topk2_kernel(const float* __restrict__ rlog, int* __restrict__ topk,
                             float* __restrict__ rowMax, float* __restrict__ rowRcp) {
  int row = blockIdx.x;                // (b*16+h)*25+m
  int l = threadIdx.x;                 // 0..63
  const float* src = rlog + (size_t)row * NN;
  float vals[17];
#pragma unroll
  for (int i = 0; i < 17; ++i) {
    int n = l + i * 64;
    vals[i] = (n < NN) ? src[n] : -INFINITY;
  }
  {
    float mx = vals[0];
#pragma unroll
    for (int i = 1; i < 17; ++i) mx = fmaxf(mx, vals[i]);
#pragma unroll
    for (int off = 32; off; off >>= 1) mx = fmaxf(mx, __shfl_xor(mx, off));
    float mxs = mx * SCALE;
    float sum = 0.f;
#pragma unroll
    for (int i = 0; i < 17; ++i) sum += __expf(vals[i] * SCALE - mxs);  // exp(-inf)=0
#pragma unroll
    for (int off = 32; off; off >>= 1) sum += __shfl_xor(sum, off);
    if (l == 0) { rowMax[row] = mxs; rowRcp[row] = 1.0f / sum; }
  }
  int* out = topk + row * 25;
  for (int r = 0; r < 25; ++r) {
    float best = vals[0]; int bi = 0;
#pragma unroll
    for (int i = 1; i < 17; ++i)
      if (vals[i] > best) { best = vals[i]; bi = i; }
    int bn = l + bi * 64;
#pragma unroll
    for (int off = 32; off; off >>= 1) {
      float ov = __shfl_down(best, off);
      int on = __shfl_down(bn, off);
      if (ov > best || (ov == best && on < bn)) { best = ov; bn = on; }
    }
    bn = __shfl(bn, 0);
    if (l == 0) out[r] = bn;
    if ((bn & 63) == l) vals[bn >> 6] = -INFINITY;
  }
}

// ---------- agent value v4: wave per (bh, m, n-slice); 8-deep MLP; atomic accumulate ----------
__global__ __launch_bounds__(256)
void agent_value4_kernel(const float* __restrict__ qkv, const float* __restrict__ rlog,
                         const float* __restrict__ rowMax, const float* __restrict__ rowRcp,
                         float* __restrict__ av) {
  int bh = blockIdx.x, mg = blockIdx.y, sl = blockIdx.z;
  int w = threadIdx.x >> 6, l = threadIdx.x & 63;
  int m = mg * 4 + w;
  if (m >= 25) return;
  int b = bh >> 4, h = bh & 15;
  int n0 = sl * 128, n1 = (sl == 7) ? NN : n0 + 128;
  const float* src = rlog + (size_t)(bh * 25 + m) * NN;   // wave-uniform -> scalar loads
  float mxs = rowMax[bh * 25 + m], rcp = rowRcp[bh * 25 + m];
  const float* vb = qkv + (size_t)b * NN * 3072 + 2048 + h * 64 + l;
  float acc[8] = {0.f, 0.f, 0.f, 0.f, 0.f, 0.f, 0.f, 0.f};
  int n = n0;
  for (; n + 8 <= n1; n += 8) {
#pragma unroll
    for (int u = 0; u < 8; ++u)
      acc[u] += __expf(src[n + u] * SCALE - mxs) * vb[(size_t)(n + u) * 3072];
  }
  for (; n < n1; ++n) acc[0] += __expf(src[n] * SCALE - mxs) * vb[(size_t)n * 3072];
  float a = ((acc[0] + acc[1]) + (acc[2] + acc[3])) + ((acc[4] + acc[5]) + (acc[6] + acc[7]));
  atomicAdd(&av[(size_t)(bh * 25 + m) * 64 + l], a * rcp);
}

// ---------- mixed attention v6: lane-per-query, chunk per block, logits in LDS (no spill) ----------
__global__ __launch_bounds__(64)
void mixed_attn6_kernel(const float* __restrict__ qkv, const float* __restrict__ gateT,
                        const int* __restrict__ topk, const float* __restrict__ av,
                        const int* __restrict__ cnt, const int* __restrict__ qlist,
                        ushort* __restrict__ attn) {
  __shared__ float sW[64 * 51];        // per-lane logit slice, odd stride (conflict-free)
  int e = blockIdx.x, bh = blockIdx.y;
  int c0 = blockIdx.z * 64;
  int ce = cnt[bh * 25 + e];
  if (c0 >= ce) return;
  int b = bh >> 4, h = bh & 15;
  int l = threadIdx.x;                 // 64 threads = 1 wave
  const int* tkp = topk + bh * 625 + e * 25;
  const int* ql = qlist + (bh * 25 + e) * NN;
  const float* qb = qkv + (size_t)b * NN * 3072 + h * 64;
  const float* avb = av + (size_t)bh * 25 * 64;
  float* myW = &sW[l * 51];

  int qi = c0 + l;
  bool act = qi < ce;
  int n = ql[act ? qi : c0];
  const float* qr = qb + (size_t)n * 3072;
  float4 q4[16];
#pragma unroll
  for (int d4 = 0; d4 < 16; ++d4) q4[d4] = *(const float4*)(qr + d4 * 4);
  float mx = -INFINITY, tot = 0.f;
  const float* gr = gateT + ((size_t)bh * NN + n) * 25;
#pragma unroll
  for (int m = 0; m < 25; ++m) {
    float v = gr[m] * SCALE;
    myW[m] = v;
    float nm = fmaxf(mx, v);
    tot = tot * __expf(mx - nm) + __expf(v - nm);
    mx = nm;
  }
#pragma unroll
  for (int j = 0; j < 25; ++j) {
    const float* kr = qb + (size_t)tkp[j] * 3072 + 1024;   // wave-uniform
    float a = 0.f;
#pragma unroll
    for (int d4 = 0; d4 < 16; ++d4) {
      float4 k4 = *(const float4*)(kr + d4 * 4);
      a += q4[d4].x * k4.x + q4[d4].y * k4.y + q4[d4].z * k4.z + q4[d4].w * k4.w;
    }
    float v = a * SCALE;
    myW[25 + j] = v;
    float nm = fmaxf(mx, v);
    tot = tot * __expf(mx - nm) + __expf(v - nm);
    mx = nm;
  }
  float rcp = 1.0f / tot;
#pragma unroll
  for (int i = 0; i < 50; ++i) myW[i] = __expf(myW[i] - mx) * rcp;   // normalized weights
  // output in two d-halves (caps live VGPRs; q4 dead by now)
#pragma unroll
  for (int half = 0; half < 2; ++half) {
    float4 o[8];
#pragma unroll
    for (int d4 = 0; d4 < 8; ++d4) o[d4] = make_float4(0.f, 0.f, 0.f, 0.f);
#pragma unroll
    for (int m = 0; m < 25; ++m) {
      const float* src = avb + m * 64 + half * 32;         // wave-uniform
      float wv = myW[m];
#pragma unroll
      for (int d4 = 0; d4 < 8; ++d4) {
        float4 a4 = *(const float4*)(src + d4 * 4);
        o[d4].x += wv * a4.x; o[d4].y += wv * a4.y;
        o[d4].z += wv * a4.z; o[d4].w += wv * a4.w;
      }
    }
#pragma unroll
    for (int j = 0; j < 25; ++j) {
      const float* src = qb + (size_t)tkp[j] * 3072 + 2048 + half * 32;  // wave-uniform
      float wv = myW[25 + j];
#pragma unroll
      for (int d4 = 0; d4 < 8; ++d4) {
        float4 a4 = *(const float4*)(src + d4 * 4);
        o[d4].x += wv * a4.x; o[d4].y += wv * a4.y;
        o[d4].z += wv * a4.z; o[d4].w += wv * a4.w;
      }
    }
    if (act) {
      ushort* orow = attn + (size_t)(b * NN + n) * 1024 + h * 64 + half * 32;
#pragma unroll
      for (int d4 = 0; d4 < 8; ++d4) {
        ushort4 u;
        u.x = f2bf(o[d4].x); u.y = f2bf(o[d4].y);
        u.z = f2bf(o[d4].z); u.w = f2bf(o[d4].w);
        *(ushort4*)(orow + d4 * 4) = u;
      }
    }
  }
}

// ---------- launch ----------
extern "C" void kernel_launch(void* const* d_in, const int* in_sizes, int n_in,
                              void* d_out, int out_size, void* d_ws, size_t ws_size,
                              hipStream_t stream) {
  const float* x = (const float*)d_in[0];
  const float* Wqkv = (const float*)d_in[1];
  const float* Wproj = (const float*)d_in[2];
  const float* bproj = (const float*)d_in[3];

  char* ws = (char*)d_ws;
  size_t off = 0;
  float* qkv = (float*)(ws + off);      off += (size_t)MROWS * 3072 * 4;    // 100,761,600
  ushort* xh = (ushort*)(ws + off);     off += (size_t)MROWS * 1024 * 2;    // 16,793,600
  ushort* xl = (ushort*)(ws + off);     off += (size_t)MROWS * 1024 * 2;
  ushort* Wth = (ushort*)(ws + off);    off += (size_t)3072 * 1024 * 2;     // 6,291,456
  ushort* Wtl = (ushort*)(ws + off);    off += (size_t)3072 * 1024 * 2;
  ushort* WpT = (ushort*)(ws + off);    off += (size_t)1024 * 1024 * 2;     // 2,097,152
  float* router = (float*)(ws + off);   off += (size_t)BB * 25 * 1024 * 4;  // 819,200
  float* rlog = (float*)(ws + off);     off += (size_t)BB * HH * 25 * NN * 4; // 13,120,000
  float* gate = (float*)(ws + off);     off += (size_t)BB * HH * 25 * NN * 4; // (unused now)
  int* topk = (int*)(ws + off);         off += (size_t)BB * HH * 25 * 25 * 4; // 320,000
  float* av = (float*)(ws + off);       off += (size_t)BB * HH * 25 * 64 * 4; // 819,200
  ushort* attn = (ushort*)(ws + off);   off += (size_t)MROWS * 1024 * 2;
  float* rowMax = (float*)(ws + off);   off += (size_t)BB * HH * 25 * 4;    // 12,800
  float* rowRcp = (float*)(ws + off);   off += (size_t)BB * HH * 25 * 4;
  (void)gate;

  // xh/xl are dead after the qkv GEMM -> reuse for routing metadata
  float* gateT = (float*)xh;                               // 13,120,000 B (<= 16,793,600)
  int* cnt = (int*)((char*)xh + 13120000);                 // 12,800 B
  int* qlist = (int*)xl;                                   // 13,120,000 B

  split_x_kernel<<<8200, 256, 0, stream>>>(x, xh, xl, 2099200);
  transpose_split_kernel<<<dim3(96, 32), dim3(32, 8), 0, stream>>>(Wqkv, Wth, Wtl, 1024, 3072);
  transpose_split_kernel<<<dim3(32, 32), dim3(32, 8), 0, stream>>>(Wproj, WpT, nullptr, 1024, 1024);
  // qkv = x @ Wqkv : bf16x3 for q,k columns (<2048), plain bf16 for v columns
  gemm_split_kernel<<<dim3(24, 65), 256, 0, stream>>>(xh, xl, Wth, Wtl, qkv, nullptr,
                                                      MROWS, 3072, 1024, 2048);
  pool_router_kernel<<<BB * 25, 1024, 0, stream>>>(qkv, router);
  hipMemsetAsync(cnt, 0, 3200 * 4, stream);
  hipMemsetAsync(av, 0, (size_t)BB * HH * 25 * 64 * 4, stream);
  rg_fused_kernel<<<dim3(128, 17), 256, 0, stream>>>(qkv, router, rlog, gateT, cnt, qlist);
  topk2_kernel<<<BB * HH * 25, 64, 0, stream>>>(rlog, topk, rowMax, rowRcp);
  agent_value4_kernel<<<dim3(128, 7, 8), 256, 0, stream>>>(qkv, rlog, rowMax, rowRcp, av);
  mixed_attn6_kernel<<<dim3(25, 128, 17), 64, 0, stream>>>(qkv, gateT, topk, av, cnt, qlist, attn);
  // out = attn @ Wproj + bproj : plain bf16
  gemm_split_kernel<<<dim3(8, 65), 256, 0, stream>>>(attn, attn, WpT, WpT, (float*)d_out, bproj,
                                                     MROWS, 1024, 1024, 0);
}